// Round 8
// baseline (545.750 us; speedup 1.0000x reference)
//
#include <hip/hip_runtime.h>
#include <math.h>

#define SB 2
#define SS 2048
#define SD 1024
#define SH 16
#define SDK 64
#define SDF 4096
#define NBS (SB*SS)

typedef unsigned short u16;
typedef unsigned int u32;
typedef __attribute__((ext_vector_type(8))) short bf16x8;
typedef __attribute__((ext_vector_type(4))) float f32x4;
typedef __attribute__((ext_vector_type(4))) unsigned short u16x4;

__device__ __forceinline__ u16 f2bf(float f) {
  u32 u = __float_as_uint(f);
  u = (u + 0x7FFFu + ((u >> 16) & 1u)) >> 16;
  return (u16)u;
}
__device__ __forceinline__ float bf2f(u16 b) {
  u32 u = ((u32)b) << 16;
  return __uint_as_float(u);
}
__device__ __forceinline__ void gld16(const void* g, void* l) {
  __builtin_amdgcn_global_load_lds(
      (const __attribute__((address_space(1))) u32*)g,
      (__attribute__((address_space(3))) u32*)l, 16, 0, 0);
}
__device__ __forceinline__ float wred_sum(float v) {
#pragma unroll
  for (int o = 32; o > 0; o >>= 1) v += __shfl_xor(v, o, 64);
  return v;
}

// ---------------- f32 -> bf16 convert for y and x in one launch ------------
__global__ __launch_bounds__(256) void cvt2_bf16_kernel(
    const float* __restrict__ y, const float* __restrict__ x,
    u16* __restrict__ ybf, u16* __restrict__ xbf) {
  const int n4 = NBS * SD / 4;
  int i = blockIdx.x * 256 + threadIdx.x;
  const float* src = y;
  u16* dst = ybf;
  if (i >= n4) { i -= n4; src = x; dst = xbf; }
  float4 v = ((const float4*)src)[i];
  u16x4 o;
  o[0] = f2bf(v.x); o[1] = f2bf(v.y); o[2] = f2bf(v.z); o[3] = f2bf(v.w);
  ((u16x4*)dst)[i] = o;
}

// ---------------- f32 [R,C] -> bf16 [C,R] transpose (batched) --------------
__global__ __launch_bounds__(256) void tr_f32_bf16_kernel(
    const float* __restrict__ in, u16* __restrict__ out, int R, int C,
    long inB, long outB) {
  __shared__ float T[32][33];
  in += (long)blockIdx.z * inB;
  out += (long)blockIdx.z * outB;
  const int r0 = blockIdx.y * 32, c0 = blockIdx.x * 32;
  const int tr = threadIdx.x >> 3, tc = (threadIdx.x & 7) * 4;
  float4 v = *(const float4*)&in[(long)(r0 + tr) * C + c0 + tc];
  T[tr][tc] = v.x; T[tr][tc + 1] = v.y; T[tr][tc + 2] = v.z; T[tr][tc + 3] = v.w;
  __syncthreads();
  u16x4 o;
  o[0] = f2bf(T[tc][tr]);     o[1] = f2bf(T[tc + 1][tr]);
  o[2] = f2bf(T[tc + 2][tr]); o[3] = f2bf(T[tc + 3][tr]);
  *(u16x4*)&out[(long)(c0 + tr) * R + r0 + tc] = o;
}

// --------- merged Wq/Wk/Wv transpose -> Bqkv rows; Q part pre-scaled -------
__global__ __launch_bounds__(256) void tr_wqkv_kernel(
    const float* __restrict__ Wq, const float* __restrict__ Wk,
    const float* __restrict__ Wv, u16* __restrict__ out) {
  __shared__ float T[32][33];
  const int z = blockIdx.z, part = z >> 4, h = z & 15;
  const float* in = (part == 0 ? Wq : (part == 1 ? Wk : Wv)) + (long)h * SD * SDK;
  u16* o = out + ((long)part * SD + h * SDK) * SD;
  const float sc = (part == 0) ? 0.125f : 1.0f;
  const int r0 = blockIdx.y * 32, c0 = blockIdx.x * 32;
  const int tr = threadIdx.x >> 3, tc = (threadIdx.x & 7) * 4;
  float4 v = *(const float4*)&in[(long)(r0 + tr) * SDK + c0 + tc];
  T[tr][tc] = v.x; T[tr][tc + 1] = v.y; T[tr][tc + 2] = v.z; T[tr][tc + 3] = v.w;
  __syncthreads();
  u16x4 ov;
  ov[0] = f2bf(T[tc][tr] * sc);     ov[1] = f2bf(T[tc + 1][tr] * sc);
  ov[2] = f2bf(T[tc + 2][tr] * sc); ov[3] = f2bf(T[tc + 3][tr] * sc);
  *(u16x4*)&o[(long)(c0 + tr) * SD + r0 + tc] = ov;
}

// ------- W2sumT[c][d] = bf16( sum_h W2[h*D+d][c] )  (fused reduce+T) -------
__global__ __launch_bounds__(256) void reduce_w2t_kernel(
    const float* __restrict__ W2, u16* __restrict__ W2sumT) {
  __shared__ float T[64][65];
  const int tid = threadIdx.x;
  const int d0 = blockIdx.y * 64, c0 = blockIdx.x * 64;
  const int dr = tid >> 2, cw = (tid & 3) * 16;
  float a[16];
#pragma unroll
  for (int i = 0; i < 16; ++i) a[i] = 0.f;
#pragma unroll
  for (int h = 0; h < SH; ++h) {
    const float* row = W2 + ((long)h * SD + d0 + dr) * SD + c0 + cw;
#pragma unroll
    for (int q = 0; q < 4; ++q) {
      float4 v = ((const float4*)row)[q];
      a[q * 4 + 0] += v.x; a[q * 4 + 1] += v.y;
      a[q * 4 + 2] += v.z; a[q * 4 + 3] += v.w;
    }
  }
#pragma unroll
  for (int i = 0; i < 16; ++i) T[dr][cw + i] = a[i];
  __syncthreads();
  const int cr = tid >> 2, dw = (tid & 3) * 16;
  u16* orow = W2sumT + (long)(c0 + cr) * SD + d0 + dw;
#pragma unroll
  for (int q = 0; q < 4; ++q) {
    u16x4 o;
    o[0] = f2bf(T[dw + q * 4 + 0][cr]);
    o[1] = f2bf(T[dw + q * 4 + 1][cr]);
    o[2] = f2bf(T[dw + q * 4 + 2][cr]);
    o[3] = f2bf(T[dw + q * 4 + 3][cr]);
    ((u16x4*)orow)[q] = o;
  }
}

// ------ pack q/k/v biases into one [3072] array (q part pre-scaled) --------
__global__ __launch_bounds__(256) void pack_bias_kernel(
    const float* __restrict__ bq, const float* __restrict__ bk,
    const float* __restrict__ bv, float* __restrict__ out) {
  int i = blockIdx.x * 256 + threadIdx.x;
  float v = (i < 1024) ? bq[i] * 0.125f
                       : ((i < 2048) ? bk[i - 1024] : bv[i - 2048]);
  out[i] = v;
}

// ---------------- V region of C3 -> VT [bh][dk][S] (bf16) ------------------
__global__ __launch_bounds__(256) void vt_kernel(const u16* __restrict__ C3,
                                                 u16* __restrict__ VT) {
  __shared__ u16 T[64][72];
  const int st = blockIdx.x, bh = blockIdx.y, b = bh >> 4, h = bh & 15;
  const u16* src = C3 + ((long)b * SS + st * 64) * 3072 + 2048 + h * 64;
#pragma unroll
  for (int it = 0; it < 4; ++it) {
    int i = threadIdx.x + it * 256;
    int r = i >> 4, c = (i & 15) * 4;
    u16x4 v = *(const u16x4*)&src[(long)r * 3072 + c];
    T[r][c] = v[0]; T[r][c + 1] = v[1]; T[r][c + 2] = v[2]; T[r][c + 3] = v[3];
  }
  __syncthreads();
#pragma unroll
  for (int it = 0; it < 4; ++it) {
    int i = threadIdx.x + it * 256;
    int dk = i >> 4, s4 = (i & 15) * 4;
    u16x4 o;
    o[0] = T[s4][dk]; o[1] = T[s4 + 1][dk];
    o[2] = T[s4 + 2][dk]; o[3] = T[s4 + 3][dk];
    *(u16x4*)&VT[((long)bh * 64 + dk) * SS + st * 64 + s4] = o;
  }
}

// ---- XCD m-clustered decode: all blocks of one (m-tile, z) share id%8 -----
__device__ __forceinline__ void swz_decode(int gx, int gy, int& bx, int& by,
                                           int& bz) {
  const int id = blockIdx.x;
  const int r = id & 7, t = id >> 3;
  const int q = t / gx, nx = t - q * gx;
  const int mz = q * 8 + r;
  bx = nx; by = mz % gy; bz = mz / gy;
}

// ---------------- bf16 MFMA GEMM 128x128: C = op(scale*A@B^T + bias) -------
// OUTF: 0=f32, 1=bf16, 2=exp->bf16. lda/ldb = row strides (split-K support).
template <int OUTF, bool RELU, bool BIAS, bool SWZ>
__global__ __launch_bounds__(256) void gemm_bt_kernel(
    const u16* __restrict__ A, const u16* __restrict__ B,
    const float* __restrict__ bias, void* __restrict__ Cp, int M, int N, int K,
    int lda, int ldb, float scale, long sA, long sB, long sC, int gx, int gy) {
  __shared__ __attribute__((aligned(16))) short As[128 * 64];
  __shared__ __attribute__((aligned(16))) short Bs[128 * 64];
  int bx, by, bz;
  if (SWZ) swz_decode(gx, gy, bx, by, bz);
  else { bx = blockIdx.x; by = blockIdx.y; bz = blockIdx.z; }
  const int tid = threadIdx.x, l = tid & 63, w = tid >> 6;
  const int wm = w & 1, wn = w >> 1;
  const long m0 = (long)by * 128, n0 = (long)bx * 128;
  A += (long)bz * sA;
  B += (long)bz * sB;
  const int r8 = l >> 3, c8 = l & 7, dc = (c8 - r8) & 7;
  const u16* Ab = A + (m0 + r8) * lda + dc * 8;
  const u16* Bb = B + (n0 + r8) * ldb + dc * 8;

  f32x4 acc[4][4];
#pragma unroll
  for (int i = 0; i < 4; ++i)
#pragma unroll
    for (int j = 0; j < 4; ++j) acc[i][j] = (f32x4)(0.0f);

  for (int k0 = 0; k0 < K; k0 += 64) {
    __syncthreads();
#pragma unroll
    for (int it = 0; it < 4; ++it) {
      const int ia = w * 4 + it;
      gld16(Ab + (long)(ia * 8) * lda + k0, As + ia * 512 + l * 8);
      gld16(Bb + (long)(ia * 8) * ldb + k0, Bs + ia * 512 + l * 8);
    }
    __syncthreads();
#pragma unroll
    for (int ks = 0; ks < 2; ++ks) {
      bf16x8 af[4], bfr[4];
#pragma unroll
      for (int i = 0; i < 4; ++i) {
        const int row = wm * 64 + i * 16 + (l & 15);
        const int slot = ((ks * 4 + (l >> 4)) + (row & 7)) & 7;
        af[i] = *(const bf16x8*)&As[row * 64 + slot * 8];
      }
#pragma unroll
      for (int j = 0; j < 4; ++j) {
        const int row = wn * 64 + j * 16 + (l & 15);
        const int slot = ((ks * 4 + (l >> 4)) + (row & 7)) & 7;
        bfr[j] = *(const bf16x8*)&Bs[row * 64 + slot * 8];
      }
#pragma unroll
      for (int i = 0; i < 4; ++i)
#pragma unroll
        for (int j = 0; j < 4; ++j)
          acc[i][j] = __builtin_amdgcn_mfma_f32_16x16x32_bf16(af[i], bfr[j],
                                                              acc[i][j], 0, 0, 0);
    }
  }
  const int cq = l >> 4, cc = l & 15;
#pragma unroll
  for (int j = 0; j < 4; ++j) {
    const long n = n0 + wn * 64 + j * 16 + cc;
    const float bb = BIAS ? bias[n] : 0.f;
#pragma unroll
    for (int i = 0; i < 4; ++i) {
      const long mrow = m0 + wm * 64 + i * 16 + cq * 4;
#pragma unroll
      for (int r = 0; r < 4; ++r) {
        float v = acc[i][j][r] * scale + bb;
        if (RELU) v = fmaxf(v, 0.f);
        const long idx = (long)bz * sC + (mrow + r) * N + n;
        if (OUTF == 0) ((float*)Cp)[idx] = v;
        else if (OUTF == 1) ((u16*)Cp)[idx] = f2bf(v);
        else ((u16*)Cp)[idx] = f2bf(__expf(v));
      }
    }
  }
}

// -------- bf16 MFMA GEMM 256x128: big-tile (FFN1). 48KB LDS, 2 blk/CU ------
template <int OUTF, bool RELU, bool BIAS>
__global__ __launch_bounds__(256) void gemm_bt256_kernel(
    const u16* __restrict__ A, const u16* __restrict__ B,
    const float* __restrict__ bias, void* __restrict__ Cp, int M, int N, int K,
    float scale) {
  __shared__ __attribute__((aligned(16))) short As[256 * 64];
  __shared__ __attribute__((aligned(16))) short Bs[128 * 64];
  const int tid = threadIdx.x, l = tid & 63, w = tid >> 6;
  const long m0 = (long)blockIdx.y * 256, n0 = (long)blockIdx.x * 128;
  const int r8 = l >> 3, c8 = l & 7, dc = (c8 - r8) & 7;
  const u16* Ab = A + (m0 + r8) * K + dc * 8;
  const u16* Bb = B + (n0 + r8) * K + dc * 8;

  f32x4 acc[4][8];
#pragma unroll
  for (int i = 0; i < 4; ++i)
#pragma unroll
    for (int j = 0; j < 8; ++j) acc[i][j] = (f32x4)(0.0f);

  for (int k0 = 0; k0 < K; k0 += 64) {
    __syncthreads();
#pragma unroll
    for (int it = 0; it < 8; ++it) {
      const int ia = w * 8 + it;
      gld16(Ab + (long)(ia * 8) * K + k0, As + ia * 512 + l * 8);
    }
#pragma unroll
    for (int it = 0; it < 4; ++it) {
      const int ib = w * 4 + it;
      gld16(Bb + (long)(ib * 8) * K + k0, Bs + ib * 512 + l * 8);
    }
    __syncthreads();
#pragma unroll
    for (int ks = 0; ks < 2; ++ks) {
      bf16x8 af[4], bfr[8];
#pragma unroll
      for (int i = 0; i < 4; ++i) {
        const int row = w * 64 + i * 16 + (l & 15);
        const int slot = ((ks * 4 + (l >> 4)) + (row & 7)) & 7;
        af[i] = *(const bf16x8*)&As[row * 64 + slot * 8];
      }
#pragma unroll
      for (int j = 0; j < 8; ++j) {
        const int row = j * 16 + (l & 15);
        const int slot = ((ks * 4 + (l >> 4)) + (row & 7)) & 7;
        bfr[j] = *(const bf16x8*)&Bs[row * 64 + slot * 8];
      }
#pragma unroll
      for (int i = 0; i < 4; ++i)
#pragma unroll
        for (int j = 0; j < 8; ++j)
          acc[i][j] = __builtin_amdgcn_mfma_f32_16x16x32_bf16(af[i], bfr[j],
                                                              acc[i][j], 0, 0, 0);
    }
  }
  const int cq = l >> 4, cc = l & 15;
#pragma unroll
  for (int j = 0; j < 8; ++j) {
    const long n = n0 + j * 16 + cc;
    const float bb = BIAS ? bias[n] : 0.f;
#pragma unroll
    for (int i = 0; i < 4; ++i) {
      const long mrow = m0 + w * 64 + i * 16 + cq * 4;
#pragma unroll
      for (int r = 0; r < 4; ++r) {
        float v = acc[i][j][r] * scale + bb;
        if (RELU) v = fmaxf(v, 0.f);
        const long idx = (mrow + r) * N + n;
        if (OUTF == 0) ((float*)Cp)[idx] = v;
        else ((u16*)Cp)[idx] = f2bf(v);
      }
    }
  }
}

// -------- bf16 MFMA GEMM 128x64 tile, double-buffered (N=1024 GEMMs) -------
// RS: multiply by per-row scale rsc[z*M + row] in epilogue.
template <int OUTF, bool RELU, bool BIAS, bool RS, bool SWZ>
__global__ __launch_bounds__(256) void gemm_bt64_kernel(
    const u16* __restrict__ A, const u16* __restrict__ B,
    const float* __restrict__ bias, void* __restrict__ Cp, int M, int N, int K,
    float scale, long sA, long sB, long sC, const float* __restrict__ rsc,
    int gx, int gy) {
  __shared__ __attribute__((aligned(16))) short As[2][128 * 64];
  __shared__ __attribute__((aligned(16))) short Bs[2][64 * 64];
  int bx, by, bz;
  if (SWZ) swz_decode(gx, gy, bx, by, bz);
  else { bx = blockIdx.x; by = blockIdx.y; bz = blockIdx.z; }
  const int tid = threadIdx.x, l = tid & 63, w = tid >> 6;
  const long m0 = (long)by * 128, n0 = (long)bx * 64;
  A += (long)bz * sA;
  B += (long)bz * sB;
  const int r8 = l >> 3, c8 = l & 7, dc = (c8 - r8) & 7;
  const u16* Ab = A + (m0 + r8) * K + dc * 8;
  const u16* Bb = B + (n0 + r8) * K + dc * 8;
  const int nk = K >> 6;

  f32x4 acc[2][4];
#pragma unroll
  for (int i = 0; i < 2; ++i)
#pragma unroll
    for (int j = 0; j < 4; ++j) acc[i][j] = (f32x4)(0.0f);

#pragma unroll
  for (int it = 0; it < 4; ++it) {
    const int ia = w * 4 + it;
    gld16(Ab + (long)(ia * 8) * K, As[0] + ia * 512 + l * 8);
  }
#pragma unroll
  for (int it = 0; it < 2; ++it) {
    const int ib = w * 2 + it;
    gld16(Bb + (long)(ib * 8) * K, Bs[0] + ib * 512 + l * 8);
  }
  __syncthreads();

  for (int kb = 0; kb < nk; ++kb) {
    const int cur = kb & 1;
    if (kb + 1 < nk) {
      const int k0n = (kb + 1) << 6;
#pragma unroll
      for (int it = 0; it < 4; ++it) {
        const int ia = w * 4 + it;
        gld16(Ab + (long)(ia * 8) * K + k0n, As[cur ^ 1] + ia * 512 + l * 8);
      }
#pragma unroll
      for (int it = 0; it < 2; ++it) {
        const int ib = w * 2 + it;
        gld16(Bb + (long)(ib * 8) * K + k0n, Bs[cur ^ 1] + ib * 512 + l * 8);
      }
    }
#pragma unroll
    for (int ks = 0; ks < 2; ++ks) {
      bf16x8 af[2], bfr[4];
#pragma unroll
      for (int i = 0; i < 2; ++i) {
        const int row = w * 32 + i * 16 + (l & 15);
        const int slot = ((ks * 4 + (l >> 4)) + (row & 7)) & 7;
        af[i] = *(const bf16x8*)&As[cur][row * 64 + slot * 8];
      }
#pragma unroll
      for (int j = 0; j < 4; ++j) {
        const int row = j * 16 + (l & 15);
        const int slot = ((ks * 4 + (l >> 4)) + (row & 7)) & 7;
        bfr[j] = *(const bf16x8*)&Bs[cur][row * 64 + slot * 8];
      }
#pragma unroll
      for (int i = 0; i < 2; ++i)
#pragma unroll
        for (int j = 0; j < 4; ++j)
          acc[i][j] = __builtin_amdgcn_mfma_f32_16x16x32_bf16(af[i], bfr[j],
                                                              acc[i][j], 0, 0, 0);
    }
    __syncthreads();
  }
  const int cq = l >> 4, cc = l & 15;
#pragma unroll
  for (int j = 0; j < 4; ++j) {
    const long n = n0 + j * 16 + cc;
    const float bb = BIAS ? bias[n] : 0.f;
#pragma unroll
    for (int i = 0; i < 2; ++i) {
      const long mrow = m0 + w * 32 + i * 16 + cq * 4;
#pragma unroll
      for (int r = 0; r < 4; ++r) {
        float v = acc[i][j][r] * scale + bb;
        if (RS) v *= rsc[(long)bz * M + mrow + r];
        if (RELU) v = fmaxf(v, 0.f);
        const long idx = (long)bz * sC + (mrow + r) * N + n;
        if (OUTF == 0) ((float*)Cp)[idx] = v;
        else ((u16*)Cp)[idx] = f2bf(v);
      }
    }
  }
}

// ---------------- MFMA flash causal self-attention, transposed-S -----------
__global__ __launch_bounds__(256) void flash_kernel(const u16* __restrict__ C3,
                                                    const u16* __restrict__ VT,
                                                    u16* __restrict__ cat) {
  __shared__ __attribute__((aligned(16))) short Qs[4096];
  __shared__ __attribute__((aligned(16))) short Ks[2][4096];
  __shared__ __attribute__((aligned(16))) short Vs[2][4096];
  __shared__ __attribute__((aligned(16))) short Ps[4096];
  const int tid = threadIdx.x, l = tid & 63, w = tid >> 6;
  const int id = blockIdx.x;
  const int bh = id & 31, pid = id >> 5;   // 32 (b,h) pairs, 16 pids
  const int b = bh >> 4, h = bh & 15;
  const u16* kb = C3 + (long)b * SS * 3072 + 1024 + h * 64;
  const u16* vb = VT + (long)bh * 64 * SS;
  const int r8 = l >> 3, c8 = l & 7, dc = (c8 - r8) & 7;
  const int cq = l >> 4, cc = l & 15;

#pragma unroll 1
  for (int phase = 0; phase < 2; ++phase) {
    const int qt = phase ? (31 - pid) : pid;
    const u16* qb = C3 + ((long)b * SS + qt * 64) * 3072 + h * 64;
#pragma unroll
    for (int it = 0; it < 2; ++it) {
      const int ia = w * 2 + it;
      gld16(qb + (long)(ia * 8 + r8) * 3072 + dc * 8, Qs + ia * 512 + l * 8);
      gld16(kb + (long)(ia * 8 + r8) * 3072 + dc * 8, Ks[0] + ia * 512 + l * 8);
      gld16(vb + (long)(ia * 8 + r8) * SS + dc * 8, Vs[0] + ia * 512 + l * 8);
    }
    f32x4 Ov[4];
    float liv = 0.f;
#pragma unroll
    for (int j = 0; j < 4; ++j) Ov[j] = (f32x4)(0.0f);
    __syncthreads();
    for (int kt = 0; kt <= qt; ++kt) {
      const int cur = kt & 1;
      if (kt < qt) {
#pragma unroll
        for (int it = 0; it < 2; ++it) {
          const int ia = w * 2 + it;
          gld16(kb + (long)((kt + 1) * 64 + ia * 8 + r8) * 3072 + dc * 8,
                Ks[cur ^ 1] + ia * 512 + l * 8);
          gld16(vb + (long)(ia * 8 + r8) * SS + (kt + 1) * 64 + dc * 8,
                Vs[cur ^ 1] + ia * 512 + l * 8);
        }
      }
      f32x4 st[4];
#pragma unroll
      for (int nt = 0; nt < 4; ++nt) st[nt] = (f32x4)(0.0f);
#pragma unroll
      for (int ks = 0; ks < 2; ++ks) {
        const int qrow = w * 16 + cc;
        const int qslot = ((ks * 4 + cq) + (qrow & 7)) & 7;
        bf16x8 qf = *(const bf16x8*)&Qs[qrow * 64 + qslot * 8];
#pragma unroll
        for (int nt = 0; nt < 4; ++nt) {
          const int krow = nt * 16 + cc;
          const int kslot = ((ks * 4 + cq) + (krow & 7)) & 7;
          bf16x8 kf = *(const bf16x8*)&Ks[cur][krow * 64 + kslot * 8];
          st[nt] = __builtin_amdgcn_mfma_f32_16x16x32_bf16(kf, qf, st[nt], 0, 0, 0);
        }
      }
      float rs = 0.f;
#pragma unroll
      for (int nt = 0; nt < 4; ++nt) {
        u16x4 pk;
#pragma unroll
        for (int r = 0; r < 4; ++r) {
          float p = __expf(st[nt][r]);
          if (kt == qt && (nt * 16 + cq * 4 + r) > (w * 16 + cc)) p = 0.f;
          rs += p;
          pk[r] = f2bf(p);
        }
        const int chunk = nt * 2 + (cq >> 1);
        const int slot = (chunk + (cc & 7)) & 7;
        *(u16x4*)&Ps[w * 1024 + cc * 64 + slot * 8 + (cq & 1) * 4] = pk;
      }
      rs += __shfl_xor(rs, 16, 64);
      rs += __shfl_xor(rs, 32, 64);
      liv += rs;
#pragma unroll
      for (int ks = 0; ks < 2; ++ks) {
        const int pslot = ((ks * 4 + cq) + (cc & 7)) & 7;
        bf16x8 pf = *(const bf16x8*)&Ps[w * 1024 + cc * 64 + pslot * 8];
#pragma unroll
        for (int dt = 0; dt < 4; ++dt) {
          const int vrow = dt * 16 + cc;
          const int vslot = ((ks * 4 + cq) + (vrow & 7)) & 7;
          bf16x8 vf = *(const bf16x8*)&Vs[cur][vrow * 64 + vslot * 8];
          Ov[dt] = __builtin_amdgcn_mfma_f32_16x16x32_bf16(pf, vf, Ov[dt], 0, 0, 0);
        }
      }
      __syncthreads();
    }
    float inv[4];
#pragma unroll
    for (int r = 0; r < 4; ++r) inv[r] = 1.0f / __shfl(liv, cq * 4 + r, 64);
    u16* cb = cat + ((long)b * SS + qt * 64 + w * 16) * SD + h * 64;
#pragma unroll
    for (int r = 0; r < 4; ++r) {
#pragma unroll
      for (int dt = 0; dt < 4; ++dt)
        cb[(long)(cq * 4 + r) * SD + dt * 16 + cc] = f2bf(Ov[dt][r] * inv[r]);
    }
  }
}

// -------- rowinv: inv[row] = 1 / sum_j P_un[row][j]  (P bf16, 2048 cols) ---
__global__ __launch_bounds__(256) void rowinv_kernel(const u16* __restrict__ P,
                                                     float* __restrict__ inv) {
  const int tid = threadIdx.x;
  const u16* row = P + (long)blockIdx.x * SS;
  u16x4 a = ((const u16x4*)row)[tid];
  u16x4 b = ((const u16x4*)row)[tid + 256];
  float s = bf2f(a[0]) + bf2f(a[1]) + bf2f(a[2]) + bf2f(a[3]) +
            bf2f(b[0]) + bf2f(b[1]) + bf2f(b[2]) + bf2f(b[3]);
  s = wred_sum(s);
  __shared__ float red[4];
  const int lane = tid & 63, wid = tid >> 6;
  if (!lane) red[wid] = s;
  __syncthreads();
  if (tid == 0) inv[blockIdx.x] = 1.0f / (red[0] + red[1] + red[2] + red[3]);
}

// ---------------- fused residual + LayerNorm ----------------
template <bool BF>
__global__ __launch_bounds__(256) void ln_res_kernel(
    const float* __restrict__ pre, const float* __restrict__ res,
    const float* __restrict__ g, const float* __restrict__ bt,
    void* __restrict__ out) {
  const int tid = threadIdx.x;
  const long row = blockIdx.x;
  float4 pv = ((const float4*)(pre + row * SD))[tid];
  float4 rv = ((const float4*)(res + row * SD))[tid];
  float x0 = pv.x + rv.x, x1 = pv.y + rv.y, x2 = pv.z + rv.z, x3 = pv.w + rv.w;
  float s = x0 + x1 + x2 + x3;
  float sq = x0 * x0 + x1 * x1 + x2 * x2 + x3 * x3;
  s = wred_sum(s);
  sq = wred_sum(sq);
  __shared__ float red[8];
  const int lane = tid & 63, wid = tid >> 6;
  if (!lane) { red[wid] = s; red[4 + wid] = sq; }
  __syncthreads();
  s = red[0] + red[1] + red[2] + red[3];
  sq = red[4] + red[5] + red[6] + red[7];
  const float mean = s * (1.0f / SD);
  const float var = sq * (1.0f / SD) - mean * mean;
  const float rstd = rsqrtf(var + 1e-5f);
  float4 gv = ((const float4*)g)[tid];
  float4 bv = ((const float4*)bt)[tid];
  float o0 = (x0 - mean) * rstd * gv.x + bv.x;
  float o1 = (x1 - mean) * rstd * gv.y + bv.y;
  float o2 = (x2 - mean) * rstd * gv.z + bv.z;
  float o3 = (x3 - mean) * rstd * gv.w + bv.w;
  if (BF) {
    u16x4 o; o[0] = f2bf(o0); o[1] = f2bf(o1); o[2] = f2bf(o2); o[3] = f2bf(o3);
    ((u16x4*)((u16*)out + row * SD))[tid] = o;
  } else {
    float4 o = make_float4(o0, o1, o2, o3);
    ((float4*)((float*)out + row * SD))[tid] = o;
  }
}

// ------ ln_res2: LN(p0 + p1 + res + bias) * g + bt (fp32 out, for ln3) -----
__global__ __launch_bounds__(256) void ln_res2_kernel(
    const float* __restrict__ p0, const float* __restrict__ p1,
    const float* __restrict__ res, const float* __restrict__ bias,
    const float* __restrict__ g, const float* __restrict__ bt,
    float* __restrict__ out) {
  const int tid = threadIdx.x;
  const long row = blockIdx.x;
  float4 a = ((const float4*)(p0 + row * SD))[tid];
  float4 b = ((const float4*)(p1 + row * SD))[tid];
  float4 rv = ((const float4*)(res + row * SD))[tid];
  float4 bi = ((const float4*)bias)[tid];
  float x0 = a.x + b.x + rv.x + bi.x, x1 = a.y + b.y + rv.y + bi.y;
  float x2 = a.z + b.z + rv.z + bi.z, x3 = a.w + b.w + rv.w + bi.w;
  float s = x0 + x1 + x2 + x3;
  float sq = x0 * x0 + x1 * x1 + x2 * x2 + x3 * x3;
  s = wred_sum(s);
  sq = wred_sum(sq);
  __shared__ float red[8];
  const int lane = tid & 63, wid = tid >> 6;
  if (!lane) { red[wid] = s; red[4 + wid] = sq; }
  __syncthreads();
  s = red[0] + red[1] + red[2] + red[3];
  sq = red[4] + red[5] + red[6] + red[7];
  const float mean = s * (1.0f / SD);
  const float var = sq * (1.0f / SD) - mean * mean;
  const float rstd = rsqrtf(var + 1e-5f);
  float4 gv = ((const float4*)g)[tid];
  float4 bv = ((const float4*)bt)[tid];
  float4 o;
  o.x = (x0 - mean) * rstd * gv.x + bv.x;
  o.y = (x1 - mean) * rstd * gv.y + bv.y;
  o.z = (x2 - mean) * rstd * gv.z + bv.z;
  o.w = (x3 - mean) * rstd * gv.w + bv.w;
  ((float4*)(out + row * SD))[tid] = o;
}

// ---------------- launch ----------------
extern "C" void kernel_launch(void* const* d_in, const int* in_sizes, int n_in,
                              void* d_out, int out_size, void* d_ws,
                              size_t ws_size, hipStream_t stream) {
  const float* x = (const float*)d_in[0];
  const float* y = (const float*)d_in[1];
  const float* Wq = (const float*)d_in[3];
  const float* bq = (const float*)d_in[4];
  const float* Wk = (const float*)d_in[5];
  const float* bk = (const float*)d_in[6];
  const float* Wv = (const float*)d_in[7];
  const float* bv = (const float*)d_in[8];
  const float* W1 = (const float*)d_in[9];
  const float* b1 = (const float*)d_in[10];
  const float* ln1_g = (const float*)d_in[11];
  const float* ln1_b = (const float*)d_in[12];
  const float* W2 = (const float*)d_in[13];
  const float* b2 = (const float*)d_in[14];
  const float* ln2_g = (const float*)d_in[15];
  const float* ln2_b = (const float*)d_in[16];
  const float* Wf1 = (const float*)d_in[17];
  const float* bf1 = (const float*)d_in[18];
  const float* Wf2 = (const float*)d_in[19];
  const float* bf2 = (const float*)d_in[20];
  const float* ln3_g = (const float*)d_in[21];
  const float* ln3_b = (const float*)d_in[22];

  char* W = (char*)d_ws;
  char* pA = W;                      // C3 -> p2un -> ffh (33.5MB)
  char* pB = pA + 33554432;          // a1pre -> a2pre -> ffn2 partial0 (16.8MB)
  char* pC = pB + 16777216;          // ybf -> VT -> a1bf -> attn2bf -> partial1[lo]
  char* pD = pC + 8388608;           // cat -> a2bf -> partial1[hi]
  char* pE = pD + 8388608;           // xbf
  char* pF = pE + 8388608;           // xT
  char* pG = pF + 8388608;           // weights
  u16* C3 = (u16*)pA;
  u16* p2un = (u16*)pA;
  u16* ffh = (u16*)pA;
  float* a1pre = (float*)pB;
  float* a2pre = (float*)pB;
  float* part0 = (float*)pB;
  float* part1 = (float*)pC;         // spans pC+pD (16.8MB)
  u16* ybf = (u16*)pC;
  u16* VT = (u16*)pC;
  u16* a1bf = (u16*)pC;
  u16* attn2bf = (u16*)pC;
  u16* cat = (u16*)pD;
  u16* a2bf = (u16*)pD;
  u16* xbf = (u16*)pE;
  u16* xT = (u16*)pF;
  u16* Bqkv = (u16*)pG;                       // 6,291,456 B
  u16* W1T = (u16*)(pG + 6291456);            // 2,097,152
  u16* W2sumT = (u16*)(pG + 8388608);         // 2,097,152
  u16* Wf1T = (u16*)(pG + 10485760);          // 8,388,608
  u16* Wf2T = (u16*)(pG + 18874368);          // 8,388,608
  float* bqkvf = (float*)(pG + 27262976);     // 12,288
  float* rowinv = (float*)(pG + 27275264);    // 16,384

  // ---- precompute / conversions ----
  cvt2_bf16_kernel<<<8192, 256, 0, stream>>>(y, x, ybf, xbf);
  tr_f32_bf16_kernel<<<dim3(SD / 32, SS / 32, SB), 256, 0, stream>>>(
      x, xT, SS, SD, (long)SS * SD, (long)SS * SD);
  tr_wqkv_kernel<<<dim3(2, 32, 48), 256, 0, stream>>>(Wq, Wk, Wv, Bqkv);
  tr_f32_bf16_kernel<<<dim3(32, 32, 1), 256, 0, stream>>>(W1, W1T, SD, SD, 0, 0);
  reduce_w2t_kernel<<<dim3(16, 16), 256, 0, stream>>>(W2, W2sumT);
  tr_f32_bf16_kernel<<<dim3(SDF / 32, SD / 32, 1), 256, 0, stream>>>(
      Wf1, Wf1T, SD, SDF, 0, 0);
  tr_f32_bf16_kernel<<<dim3(SD / 32, SDF / 32, 1), 256, 0, stream>>>(
      Wf2, Wf2T, SDF, SD, 0, 0);
  pack_bias_kernel<<<12, 256, 0, stream>>>(bq, bk, bv, bqkvf);

  // ---- fused QKV projection: [4096,1024] @ [3072,1024]^T -> C3 bf16 ----
  gemm_bt_kernel<1, false, true, false><<<dim3(24, 32, 1), 256, 0, stream>>>(
      ybf, Bqkv, bqkvf, C3, NBS, 3072, SD, SD, SD, 1.f, 0, 0, 0, 0, 0);
  vt_kernel<<<dim3(SS / 64, SB * SH), 256, 0, stream>>>(C3, VT);
  // ---- causal flash self-attention (balanced pairs, XCD-clustered) ----
  flash_kernel<<<512, 256, 0, stream>>>(C3, VT, cat);
  // ---- a1 = LN(y + cat@W1 + b1) -> bf16  (m-clustered swizzle) ----
  gemm_bt64_kernel<0, false, true, false, true><<<512, 256, 0, stream>>>(
      cat, W1T, b1, a1pre, NBS, SD, SD, 1.f, 0, 0, 0, nullptr, 16, 32);
  ln_res_kernel<true><<<NBS, 256, 0, stream>>>(a1pre, y, ln1_g, ln1_b, a1bf);
  // ---- cross-attention: P_un = exp(a1@x^T/8) bf16; rowinv; attn2 w/ scale --
  gemm_bt_kernel<2, false, false, false><<<dim3(16, 16, SB), 256, 0, stream>>>(
      a1bf, xbf, nullptr, p2un, SS, SS, SD, SD, SD, 0.125f, (long)SS * SD,
      (long)SS * SD, (long)SS * SS, 0, 0);
  rowinv_kernel<<<NBS, 256, 0, stream>>>(p2un, rowinv);
  gemm_bt64_kernel<1, false, false, true, true><<<512, 256, 0, stream>>>(
      p2un, xT, nullptr, attn2bf, SS, SD, SS, 1.f, (long)SS * SS,
      (long)SS * SD, (long)SS * SD, rowinv, 16, 16);
  // ---- a2 = LN(y + attn2@W2sum + b2) ----
  gemm_bt64_kernel<0, false, true, false, true><<<512, 256, 0, stream>>>(
      attn2bf, W2sumT, b2, a2pre, NBS, SD, SD, 1.f, 0, 0, 0, nullptr, 16, 32);
  ln_res_kernel<true><<<NBS, 256, 0, stream>>>(a2pre, y, ln2_g, ln2_b, a2bf);
  // ---- FFN1: 256x128 big tile ----
  gemm_bt256_kernel<1, true, true><<<dim3(SDF / 128, NBS / 256), 256, 0,
                                    stream>>>(a2bf, Wf1T, bf1, ffh, NBS, SDF,
                                              SD, 1.f);
  // ---- FFN2 split-K=2, m-clustered swizzle ----
  gemm_bt_kernel<0, false, false, true><<<512, 256, 0, stream>>>(
      ffh, Wf2T, nullptr, part0, NBS, SD, SDF / 2, SDF, SDF, 1.f, SDF / 2,
      SDF / 2, (long)NBS * SD, 8, 32);
  ln_res2_kernel<<<NBS, 256, 0, stream>>>(part0, part1, y, bf2, ln3_g, ln3_b,
                                          (float*)d_out);
}

// Round 9
// 530.155 us; speedup vs baseline: 1.0294x; 1.0294x over previous
//
#include <hip/hip_runtime.h>
#include <math.h>

#define SB 2
#define SS 2048
#define SD 1024
#define SH 16
#define SDK 64
#define SDF 4096
#define NBS (SB*SS)

typedef unsigned short u16;
typedef unsigned int u32;
typedef __attribute__((ext_vector_type(8))) short bf16x8;
typedef __attribute__((ext_vector_type(4))) float f32x4;
typedef __attribute__((ext_vector_type(4))) unsigned short u16x4;

__device__ __forceinline__ u16 f2bf(float f) {
  u32 u = __float_as_uint(f);
  u = (u + 0x7FFFu + ((u >> 16) & 1u)) >> 16;
  return (u16)u;
}
__device__ __forceinline__ float bf2f(u16 b) {
  u32 u = ((u32)b) << 16;
  return __uint_as_float(u);
}
__device__ __forceinline__ void gld16(const void* g, void* l) {
  __builtin_amdgcn_global_load_lds(
      (const __attribute__((address_space(1))) u32*)g,
      (__attribute__((address_space(3))) u32*)l, 16, 0, 0);
}
__device__ __forceinline__ float wred_sum(float v) {
#pragma unroll
  for (int o = 32; o > 0; o >>= 1) v += __shfl_xor(v, o, 64);
  return v;
}

// ---------------- f32 -> bf16 convert for y and x in one launch ------------
__global__ __launch_bounds__(256) void cvt2_bf16_kernel(
    const float* __restrict__ y, const float* __restrict__ x,
    u16* __restrict__ ybf, u16* __restrict__ xbf) {
  const int n4 = NBS * SD / 4;
  int i = blockIdx.x * 256 + threadIdx.x;
  const float* src = y;
  u16* dst = ybf;
  if (i >= n4) { i -= n4; src = x; dst = xbf; }
  float4 v = ((const float4*)src)[i];
  u16x4 o;
  o[0] = f2bf(v.x); o[1] = f2bf(v.y); o[2] = f2bf(v.z); o[3] = f2bf(v.w);
  ((u16x4*)dst)[i] = o;
}

// ---------------- f32 [R,C] -> bf16 [C,R] transpose (batched) --------------
__global__ __launch_bounds__(256) void tr_f32_bf16_kernel(
    const float* __restrict__ in, u16* __restrict__ out, int R, int C,
    long inB, long outB) {
  __shared__ float T[32][33];
  in += (long)blockIdx.z * inB;
  out += (long)blockIdx.z * outB;
  const int r0 = blockIdx.y * 32, c0 = blockIdx.x * 32;
  const int tr = threadIdx.x >> 3, tc = (threadIdx.x & 7) * 4;
  float4 v = *(const float4*)&in[(long)(r0 + tr) * C + c0 + tc];
  T[tr][tc] = v.x; T[tr][tc + 1] = v.y; T[tr][tc + 2] = v.z; T[tr][tc + 3] = v.w;
  __syncthreads();
  u16x4 o;
  o[0] = f2bf(T[tc][tr]);     o[1] = f2bf(T[tc + 1][tr]);
  o[2] = f2bf(T[tc + 2][tr]); o[3] = f2bf(T[tc + 3][tr]);
  *(u16x4*)&out[(long)(c0 + tr) * R + r0 + tc] = o;
}

// --------- merged Wq/Wk/Wv transpose -> Bqkv rows; Q part pre-scaled -------
__global__ __launch_bounds__(256) void tr_wqkv_kernel(
    const float* __restrict__ Wq, const float* __restrict__ Wk,
    const float* __restrict__ Wv, u16* __restrict__ out) {
  __shared__ float T[32][33];
  const int z = blockIdx.z, part = z >> 4, h = z & 15;
  const float* in = (part == 0 ? Wq : (part == 1 ? Wk : Wv)) + (long)h * SD * SDK;
  u16* o = out + ((long)part * SD + h * SDK) * SD;
  const float sc = (part == 0) ? 0.125f : 1.0f;
  const int r0 = blockIdx.y * 32, c0 = blockIdx.x * 32;
  const int tr = threadIdx.x >> 3, tc = (threadIdx.x & 7) * 4;
  float4 v = *(const float4*)&in[(long)(r0 + tr) * SDK + c0 + tc];
  T[tr][tc] = v.x; T[tr][tc + 1] = v.y; T[tr][tc + 2] = v.z; T[tr][tc + 3] = v.w;
  __syncthreads();
  u16x4 ov;
  ov[0] = f2bf(T[tc][tr] * sc);     ov[1] = f2bf(T[tc + 1][tr] * sc);
  ov[2] = f2bf(T[tc + 2][tr] * sc); ov[3] = f2bf(T[tc + 3][tr] * sc);
  *(u16x4*)&o[(long)(c0 + tr) * SD + r0 + tc] = ov;
}

// ------- W2sumT[c][d] = bf16( sum_h W2[h*D+d][c] )  (fused reduce+T) -------
__global__ __launch_bounds__(256) void reduce_w2t_kernel(
    const float* __restrict__ W2, u16* __restrict__ W2sumT) {
  __shared__ float T[64][65];
  const int tid = threadIdx.x;
  const int d0 = blockIdx.y * 64, c0 = blockIdx.x * 64;
  const int dr = tid >> 2, cw = (tid & 3) * 16;
  float a[16];
#pragma unroll
  for (int i = 0; i < 16; ++i) a[i] = 0.f;
#pragma unroll
  for (int h = 0; h < SH; ++h) {
    const float* row = W2 + ((long)h * SD + d0 + dr) * SD + c0 + cw;
#pragma unroll
    for (int q = 0; q < 4; ++q) {
      float4 v = ((const float4*)row)[q];
      a[q * 4 + 0] += v.x; a[q * 4 + 1] += v.y;
      a[q * 4 + 2] += v.z; a[q * 4 + 3] += v.w;
    }
  }
#pragma unroll
  for (int i = 0; i < 16; ++i) T[dr][cw + i] = a[i];
  __syncthreads();
  const int cr = tid >> 2, dw = (tid & 3) * 16;
  u16* orow = W2sumT + (long)(c0 + cr) * SD + d0 + dw;
#pragma unroll
  for (int q = 0; q < 4; ++q) {
    u16x4 o;
    o[0] = f2bf(T[dw + q * 4 + 0][cr]);
    o[1] = f2bf(T[dw + q * 4 + 1][cr]);
    o[2] = f2bf(T[dw + q * 4 + 2][cr]);
    o[3] = f2bf(T[dw + q * 4 + 3][cr]);
    ((u16x4*)orow)[q] = o;
  }
}

// ------ pack q/k/v biases into one [3072] array (q part pre-scaled) --------
__global__ __launch_bounds__(256) void pack_bias_kernel(
    const float* __restrict__ bq, const float* __restrict__ bk,
    const float* __restrict__ bv, float* __restrict__ out) {
  int i = blockIdx.x * 256 + threadIdx.x;
  float v = (i < 1024) ? bq[i] * 0.125f
                       : ((i < 2048) ? bk[i - 1024] : bv[i - 2048]);
  out[i] = v;
}

// ---------------- V region of C3 -> VT [bh][dk][S] (bf16) ------------------
__global__ __launch_bounds__(256) void vt_kernel(const u16* __restrict__ C3,
                                                 u16* __restrict__ VT) {
  __shared__ u16 T[64][72];
  const int st = blockIdx.x, bh = blockIdx.y, b = bh >> 4, h = bh & 15;
  const u16* src = C3 + ((long)b * SS + st * 64) * 3072 + 2048 + h * 64;
#pragma unroll
  for (int it = 0; it < 4; ++it) {
    int i = threadIdx.x + it * 256;
    int r = i >> 4, c = (i & 15) * 4;
    u16x4 v = *(const u16x4*)&src[(long)r * 3072 + c];
    T[r][c] = v[0]; T[r][c + 1] = v[1]; T[r][c + 2] = v[2]; T[r][c + 3] = v[3];
  }
  __syncthreads();
#pragma unroll
  for (int it = 0; it < 4; ++it) {
    int i = threadIdx.x + it * 256;
    int dk = i >> 4, s4 = (i & 15) * 4;
    u16x4 o;
    o[0] = T[s4][dk]; o[1] = T[s4 + 1][dk];
    o[2] = T[s4 + 2][dk]; o[3] = T[s4 + 3][dk];
    *(u16x4*)&VT[((long)bh * 64 + dk) * SS + st * 64 + s4] = o;
  }
}

// ---- XCD m-clustered decode: all blocks of one (m-tile, z) share id%8 -----
__device__ __forceinline__ void swz_decode(int gx, int gy, int& bx, int& by,
                                           int& bz) {
  const int id = blockIdx.x;
  const int r = id & 7, t = id >> 3;
  const int q = t / gx, nx = t - q * gx;
  const int mz = q * 8 + r;
  bx = nx; by = mz % gy; bz = mz / gy;
}

// ---------------- bf16 MFMA GEMM 128x128: C = op(scale*A@B^T + bias) -------
// OUTF: 0=f32, 1=bf16, 2=exp->bf16. lda/ldb = row strides (split-K support).
template <int OUTF, bool RELU, bool BIAS, bool SWZ>
__global__ __launch_bounds__(256) void gemm_bt_kernel(
    const u16* __restrict__ A, const u16* __restrict__ B,
    const float* __restrict__ bias, void* __restrict__ Cp, int M, int N, int K,
    int lda, int ldb, float scale, long sA, long sB, long sC, int gx, int gy) {
  __shared__ __attribute__((aligned(16))) short As[128 * 64];
  __shared__ __attribute__((aligned(16))) short Bs[128 * 64];
  int bx, by, bz;
  if (SWZ) swz_decode(gx, gy, bx, by, bz);
  else { bx = blockIdx.x; by = blockIdx.y; bz = blockIdx.z; }
  const int tid = threadIdx.x, l = tid & 63, w = tid >> 6;
  const int wm = w & 1, wn = w >> 1;
  const long m0 = (long)by * 128, n0 = (long)bx * 128;
  A += (long)bz * sA;
  B += (long)bz * sB;
  const int r8 = l >> 3, c8 = l & 7, dc = (c8 - r8) & 7;
  const u16* Ab = A + (m0 + r8) * lda + dc * 8;
  const u16* Bb = B + (n0 + r8) * ldb + dc * 8;

  f32x4 acc[4][4];
#pragma unroll
  for (int i = 0; i < 4; ++i)
#pragma unroll
    for (int j = 0; j < 4; ++j) acc[i][j] = (f32x4)(0.0f);

  for (int k0 = 0; k0 < K; k0 += 64) {
    __syncthreads();
#pragma unroll
    for (int it = 0; it < 4; ++it) {
      const int ia = w * 4 + it;
      gld16(Ab + (long)(ia * 8) * lda + k0, As + ia * 512 + l * 8);
      gld16(Bb + (long)(ia * 8) * ldb + k0, Bs + ia * 512 + l * 8);
    }
    __syncthreads();
#pragma unroll
    for (int ks = 0; ks < 2; ++ks) {
      bf16x8 af[4], bfr[4];
#pragma unroll
      for (int i = 0; i < 4; ++i) {
        const int row = wm * 64 + i * 16 + (l & 15);
        const int slot = ((ks * 4 + (l >> 4)) + (row & 7)) & 7;
        af[i] = *(const bf16x8*)&As[row * 64 + slot * 8];
      }
#pragma unroll
      for (int j = 0; j < 4; ++j) {
        const int row = wn * 64 + j * 16 + (l & 15);
        const int slot = ((ks * 4 + (l >> 4)) + (row & 7)) & 7;
        bfr[j] = *(const bf16x8*)&Bs[row * 64 + slot * 8];
      }
#pragma unroll
      for (int i = 0; i < 4; ++i)
#pragma unroll
        for (int j = 0; j < 4; ++j)
          acc[i][j] = __builtin_amdgcn_mfma_f32_16x16x32_bf16(af[i], bfr[j],
                                                              acc[i][j], 0, 0, 0);
    }
  }
  const int cq = l >> 4, cc = l & 15;
#pragma unroll
  for (int j = 0; j < 4; ++j) {
    const long n = n0 + wn * 64 + j * 16 + cc;
    const float bb = BIAS ? bias[n] : 0.f;
#pragma unroll
    for (int i = 0; i < 4; ++i) {
      const long mrow = m0 + wm * 64 + i * 16 + cq * 4;
#pragma unroll
      for (int r = 0; r < 4; ++r) {
        float v = acc[i][j][r] * scale + bb;
        if (RELU) v = fmaxf(v, 0.f);
        const long idx = (long)bz * sC + (mrow + r) * N + n;
        if (OUTF == 0) ((float*)Cp)[idx] = v;
        else if (OUTF == 1) ((u16*)Cp)[idx] = f2bf(v);
        else ((u16*)Cp)[idx] = f2bf(__expf(v));
      }
    }
  }
}

// -------- bf16 MFMA GEMM 128x64 tile, double-buffered (N=1024 GEMMs) -------
// RS: multiply by per-row scale rsc[z*M + row] in epilogue.
template <int OUTF, bool RELU, bool BIAS, bool RS, bool SWZ>
__global__ __launch_bounds__(256) void gemm_bt64_kernel(
    const u16* __restrict__ A, const u16* __restrict__ B,
    const float* __restrict__ bias, void* __restrict__ Cp, int M, int N, int K,
    float scale, long sA, long sB, long sC, const float* __restrict__ rsc,
    int gx, int gy) {
  __shared__ __attribute__((aligned(16))) short As[2][128 * 64];
  __shared__ __attribute__((aligned(16))) short Bs[2][64 * 64];
  int bx, by, bz;
  if (SWZ) swz_decode(gx, gy, bx, by, bz);
  else { bx = blockIdx.x; by = blockIdx.y; bz = blockIdx.z; }
  const int tid = threadIdx.x, l = tid & 63, w = tid >> 6;
  const long m0 = (long)by * 128, n0 = (long)bx * 64;
  A += (long)bz * sA;
  B += (long)bz * sB;
  const int r8 = l >> 3, c8 = l & 7, dc = (c8 - r8) & 7;
  const u16* Ab = A + (m0 + r8) * K + dc * 8;
  const u16* Bb = B + (n0 + r8) * K + dc * 8;
  const int nk = K >> 6;

  f32x4 acc[2][4];
#pragma unroll
  for (int i = 0; i < 2; ++i)
#pragma unroll
    for (int j = 0; j < 4; ++j) acc[i][j] = (f32x4)(0.0f);

#pragma unroll
  for (int it = 0; it < 4; ++it) {
    const int ia = w * 4 + it;
    gld16(Ab + (long)(ia * 8) * K, As[0] + ia * 512 + l * 8);
  }
#pragma unroll
  for (int it = 0; it < 2; ++it) {
    const int ib = w * 2 + it;
    gld16(Bb + (long)(ib * 8) * K, Bs[0] + ib * 512 + l * 8);
  }
  __syncthreads();

  for (int kb = 0; kb < nk; ++kb) {
    const int cur = kb & 1;
    if (kb + 1 < nk) {
      const int k0n = (kb + 1) << 6;
#pragma unroll
      for (int it = 0; it < 4; ++it) {
        const int ia = w * 4 + it;
        gld16(Ab + (long)(ia * 8) * K + k0n, As[cur ^ 1] + ia * 512 + l * 8);
      }
#pragma unroll
      for (int it = 0; it < 2; ++it) {
        const int ib = w * 2 + it;
        gld16(Bb + (long)(ib * 8) * K + k0n, Bs[cur ^ 1] + ib * 512 + l * 8);
      }
    }
#pragma unroll
    for (int ks = 0; ks < 2; ++ks) {
      bf16x8 af[2], bfr[4];
#pragma unroll
      for (int i = 0; i < 2; ++i) {
        const int row = w * 32 + i * 16 + (l & 15);
        const int slot = ((ks * 4 + (l >> 4)) + (row & 7)) & 7;
        af[i] = *(const bf16x8*)&As[cur][row * 64 + slot * 8];
      }
#pragma unroll
      for (int j = 0; j < 4; ++j) {
        const int row = j * 16 + (l & 15);
        const int slot = ((ks * 4 + (l >> 4)) + (row & 7)) & 7;
        bfr[j] = *(const bf16x8*)&Bs[cur][row * 64 + slot * 8];
      }
#pragma unroll
      for (int i = 0; i < 2; ++i)
#pragma unroll
        for (int j = 0; j < 4; ++j)
          acc[i][j] = __builtin_amdgcn_mfma_f32_16x16x32_bf16(af[i], bfr[j],
                                                              acc[i][j], 0, 0, 0);
    }
    __syncthreads();
  }
  const int cq = l >> 4, cc = l & 15;
#pragma unroll
  for (int j = 0; j < 4; ++j) {
    const long n = n0 + j * 16 + cc;
    const float bb = BIAS ? bias[n] : 0.f;
#pragma unroll
    for (int i = 0; i < 2; ++i) {
      const long mrow = m0 + w * 32 + i * 16 + cq * 4;
#pragma unroll
      for (int r = 0; r < 4; ++r) {
        float v = acc[i][j][r] * scale + bb;
        if (RS) v *= rsc[(long)bz * M + mrow + r];
        if (RELU) v = fmaxf(v, 0.f);
        const long idx = (long)bz * sC + (mrow + r) * N + n;
        if (OUTF == 0) ((float*)Cp)[idx] = v;
        else ((u16*)Cp)[idx] = f2bf(v);
      }
    }
  }
}

// ---------------- MFMA flash causal self-attention, transposed-S -----------
// 1024 blocks: one q-tile each (qt = id>>5, bh = id&31 keeps XCD locality);
// 48KB LDS -> 3 blocks/CU resident -> better latency hiding than paired-512.
__global__ __launch_bounds__(256) void flash_kernel(const u16* __restrict__ C3,
                                                    const u16* __restrict__ VT,
                                                    u16* __restrict__ cat) {
  __shared__ __attribute__((aligned(16))) short Qs[4096];
  __shared__ __attribute__((aligned(16))) short Ks[2][4096];
  __shared__ __attribute__((aligned(16))) short Vs[2][4096];
  __shared__ __attribute__((aligned(16))) short Ps[4096];
  const int tid = threadIdx.x, l = tid & 63, w = tid >> 6;
  const int id = blockIdx.x;
  const int bh = id & 31, qt = id >> 5;   // 32 (b,h) pairs, 32 q-tiles
  const int b = bh >> 4, h = bh & 15;
  const u16* kb = C3 + (long)b * SS * 3072 + 1024 + h * 64;
  const u16* vb = VT + (long)bh * 64 * SS;
  const int r8 = l >> 3, c8 = l & 7, dc = (c8 - r8) & 7;
  const int cq = l >> 4, cc = l & 15;

  const u16* qb = C3 + ((long)b * SS + qt * 64) * 3072 + h * 64;
#pragma unroll
  for (int it = 0; it < 2; ++it) {
    const int ia = w * 2 + it;
    gld16(qb + (long)(ia * 8 + r8) * 3072 + dc * 8, Qs + ia * 512 + l * 8);
    gld16(kb + (long)(ia * 8 + r8) * 3072 + dc * 8, Ks[0] + ia * 512 + l * 8);
    gld16(vb + (long)(ia * 8 + r8) * SS + dc * 8, Vs[0] + ia * 512 + l * 8);
  }
  f32x4 Ov[4];
  float liv = 0.f;
#pragma unroll
  for (int j = 0; j < 4; ++j) Ov[j] = (f32x4)(0.0f);
  __syncthreads();
  for (int kt = 0; kt <= qt; ++kt) {
    const int cur = kt & 1;
    if (kt < qt) {
#pragma unroll
      for (int it = 0; it < 2; ++it) {
        const int ia = w * 2 + it;
        gld16(kb + (long)((kt + 1) * 64 + ia * 8 + r8) * 3072 + dc * 8,
              Ks[cur ^ 1] + ia * 512 + l * 8);
        gld16(vb + (long)(ia * 8 + r8) * SS + (kt + 1) * 64 + dc * 8,
              Vs[cur ^ 1] + ia * 512 + l * 8);
      }
    }
    // S^T = K Q^T : D row = key (nt*16 + cq*4 + r), D col = query (w*16+cc)
    f32x4 st[4];
#pragma unroll
    for (int nt = 0; nt < 4; ++nt) st[nt] = (f32x4)(0.0f);
#pragma unroll
    for (int ks = 0; ks < 2; ++ks) {
      const int qrow = w * 16 + cc;
      const int qslot = ((ks * 4 + cq) + (qrow & 7)) & 7;
      bf16x8 qf = *(const bf16x8*)&Qs[qrow * 64 + qslot * 8];
#pragma unroll
      for (int nt = 0; nt < 4; ++nt) {
        const int krow = nt * 16 + cc;
        const int kslot = ((ks * 4 + cq) + (krow & 7)) & 7;
        bf16x8 kf = *(const bf16x8*)&Ks[cur][krow * 64 + kslot * 8];
        st[nt] = __builtin_amdgcn_mfma_f32_16x16x32_bf16(kf, qf, st[nt], 0, 0, 0);
      }
    }
    // p = exp(s) (no max subtraction: scores bounded), mask, row-sum
    float rs = 0.f;
#pragma unroll
    for (int nt = 0; nt < 4; ++nt) {
      u16x4 pk;
#pragma unroll
      for (int r = 0; r < 4; ++r) {
        float p = __expf(st[nt][r]);
        if (kt == qt && (nt * 16 + cq * 4 + r) > (w * 16 + cc)) p = 0.f;
        rs += p;
        pk[r] = f2bf(p);
      }
      const int chunk = nt * 2 + (cq >> 1);
      const int slot = (chunk + (cc & 7)) & 7;
      *(u16x4*)&Ps[w * 1024 + cc * 64 + slot * 8 + (cq & 1) * 4] = pk;
    }
    rs += __shfl_xor(rs, 16, 64);
    rs += __shfl_xor(rs, 32, 64);
    liv += rs;
    // O += P V  (P as A-operand: rows=16 queries of this wave, k=64 keys)
#pragma unroll
    for (int ks = 0; ks < 2; ++ks) {
      const int pslot = ((ks * 4 + cq) + (cc & 7)) & 7;
      bf16x8 pf = *(const bf16x8*)&Ps[w * 1024 + cc * 64 + pslot * 8];
#pragma unroll
      for (int dt = 0; dt < 4; ++dt) {
        const int vrow = dt * 16 + cc;
        const int vslot = ((ks * 4 + cq) + (vrow & 7)) & 7;
        bf16x8 vf = *(const bf16x8*)&Vs[cur][vrow * 64 + vslot * 8];
        Ov[dt] = __builtin_amdgcn_mfma_f32_16x16x32_bf16(pf, vf, Ov[dt], 0, 0, 0);
      }
    }
    __syncthreads();
  }
  // epilogue: lane cc holds row-sum for query w*16+cc; redistribute
  float inv[4];
#pragma unroll
  for (int r = 0; r < 4; ++r) inv[r] = 1.0f / __shfl(liv, cq * 4 + r, 64);
  u16* cb = cat + ((long)b * SS + qt * 64 + w * 16) * SD + h * 64;
#pragma unroll
  for (int r = 0; r < 4; ++r) {
#pragma unroll
    for (int dt = 0; dt < 4; ++dt)
      cb[(long)(cq * 4 + r) * SD + dt * 16 + cc] = f2bf(Ov[dt][r] * inv[r]);
  }
}

// -------- rowinv: inv[row] = 1 / sum_j P_un[row][j]  (P bf16, 2048 cols) ---
__global__ __launch_bounds__(256) void rowinv_kernel(const u16* __restrict__ P,
                                                     float* __restrict__ inv) {
  const int tid = threadIdx.x;
  const u16* row = P + (long)blockIdx.x * SS;
  u16x4 a = ((const u16x4*)row)[tid];
  u16x4 b = ((const u16x4*)row)[tid + 256];
  float s = bf2f(a[0]) + bf2f(a[1]) + bf2f(a[2]) + bf2f(a[3]) +
            bf2f(b[0]) + bf2f(b[1]) + bf2f(b[2]) + bf2f(b[3]);
  s = wred_sum(s);
  __shared__ float red[4];
  const int lane = tid & 63, wid = tid >> 6;
  if (!lane) red[wid] = s;
  __syncthreads();
  if (tid == 0) inv[blockIdx.x] = 1.0f / (red[0] + red[1] + red[2] + red[3]);
}

// ---------------- fused residual + LayerNorm ----------------
template <bool BF>
__global__ __launch_bounds__(256) void ln_res_kernel(
    const float* __restrict__ pre, const float* __restrict__ res,
    const float* __restrict__ g, const float* __restrict__ bt,
    void* __restrict__ out) {
  const int tid = threadIdx.x;
  const long row = blockIdx.x;
  float4 pv = ((const float4*)(pre + row * SD))[tid];
  float4 rv = ((const float4*)(res + row * SD))[tid];
  float x0 = pv.x + rv.x, x1 = pv.y + rv.y, x2 = pv.z + rv.z, x3 = pv.w + rv.w;
  float s = x0 + x1 + x2 + x3;
  float sq = x0 * x0 + x1 * x1 + x2 * x2 + x3 * x3;
  s = wred_sum(s);
  sq = wred_sum(sq);
  __shared__ float red[8];
  const int lane = tid & 63, wid = tid >> 6;
  if (!lane) { red[wid] = s; red[4 + wid] = sq; }
  __syncthreads();
  s = red[0] + red[1] + red[2] + red[3];
  sq = red[4] + red[5] + red[6] + red[7];
  const float mean = s * (1.0f / SD);
  const float var = sq * (1.0f / SD) - mean * mean;
  const float rstd = rsqrtf(var + 1e-5f);
  float4 gv = ((const float4*)g)[tid];
  float4 bv = ((const float4*)bt)[tid];
  float o0 = (x0 - mean) * rstd * gv.x + bv.x;
  float o1 = (x1 - mean) * rstd * gv.y + bv.y;
  float o2 = (x2 - mean) * rstd * gv.z + bv.z;
  float o3 = (x3 - mean) * rstd * gv.w + bv.w;
  if (BF) {
    u16x4 o; o[0] = f2bf(o0); o[1] = f2bf(o1); o[2] = f2bf(o2); o[3] = f2bf(o3);
    ((u16x4*)((u16*)out + row * SD))[tid] = o;
  } else {
    float4 o = make_float4(o0, o1, o2, o3);
    ((float4*)((float*)out + row * SD))[tid] = o;
  }
}

// ------ ln_res2: LN(p0 + p1 + res + bias) * g + bt (fp32 out, for ln3) -----
__global__ __launch_bounds__(256) void ln_res2_kernel(
    const float* __restrict__ p0, const float* __restrict__ p1,
    const float* __restrict__ res, const float* __restrict__ bias,
    const float* __restrict__ g, const float* __restrict__ bt,
    float* __restrict__ out) {
  const int tid = threadIdx.x;
  const long row = blockIdx.x;
  float4 a = ((const float4*)(p0 + row * SD))[tid];
  float4 b = ((const float4*)(p1 + row * SD))[tid];
  float4 rv = ((const float4*)(res + row * SD))[tid];
  float4 bi = ((const float4*)bias)[tid];
  float x0 = a.x + b.x + rv.x + bi.x, x1 = a.y + b.y + rv.y + bi.y;
  float x2 = a.z + b.z + rv.z + bi.z, x3 = a.w + b.w + rv.w + bi.w;
  float s = x0 + x1 + x2 + x3;
  float sq = x0 * x0 + x1 * x1 + x2 * x2 + x3 * x3;
  s = wred_sum(s);
  sq = wred_sum(sq);
  __shared__ float red[8];
  const int lane = tid & 63, wid = tid >> 6;
  if (!lane) { red[wid] = s; red[4 + wid] = sq; }
  __syncthreads();
  s = red[0] + red[1] + red[2] + red[3];
  sq = red[4] + red[5] + red[6] + red[7];
  const float mean = s * (1.0f / SD);
  const float var = sq * (1.0f / SD) - mean * mean;
  const float rstd = rsqrtf(var + 1e-5f);
  float4 gv = ((const float4*)g)[tid];
  float4 bv = ((const float4*)bt)[tid];
  float4 o;
  o.x = (x0 - mean) * rstd * gv.x + bv.x;
  o.y = (x1 - mean) * rstd * gv.y + bv.y;
  o.z = (x2 - mean) * rstd * gv.z + bv.z;
  o.w = (x3 - mean) * rstd * gv.w + bv.w;
  ((float4*)(out + row * SD))[tid] = o;
}

// ---------------- launch ----------------
extern "C" void kernel_launch(void* const* d_in, const int* in_sizes, int n_in,
                              void* d_out, int out_size, void* d_ws,
                              size_t ws_size, hipStream_t stream) {
  const float* x = (const float*)d_in[0];
  const float* y = (const float*)d_in[1];
  const float* Wq = (const float*)d_in[3];
  const float* bq = (const float*)d_in[4];
  const float* Wk = (const float*)d_in[5];
  const float* bk = (const float*)d_in[6];
  const float* Wv = (const float*)d_in[7];
  const float* bv = (const float*)d_in[8];
  const float* W1 = (const float*)d_in[9];
  const float* b1 = (const float*)d_in[10];
  const float* ln1_g = (const float*)d_in[11];
  const float* ln1_b = (const float*)d_in[12];
  const float* W2 = (const float*)d_in[13];
  const float* b2 = (const float*)d_in[14];
  const float* ln2_g = (const float*)d_in[15];
  const float* ln2_b = (const float*)d_in[16];
  const float* Wf1 = (const float*)d_in[17];
  const float* bf1 = (const float*)d_in[18];
  const float* Wf2 = (const float*)d_in[19];
  const float* bf2 = (const float*)d_in[20];
  const float* ln3_g = (const float*)d_in[21];
  const float* ln3_b = (const float*)d_in[22];

  char* W = (char*)d_ws;
  char* pA = W;                      // C3 -> p2un -> ffh (33.5MB)
  char* pB = pA + 33554432;          // a1pre -> a2pre -> ffn2 partial0 (16.8MB)
  char* pC = pB + 16777216;          // ybf -> VT -> a1bf -> attn2bf -> partial1[lo]
  char* pD = pC + 8388608;           // cat -> a2bf -> partial1[hi]
  char* pE = pD + 8388608;           // xbf
  char* pF = pE + 8388608;           // xT
  char* pG = pF + 8388608;           // weights
  u16* C3 = (u16*)pA;
  u16* p2un = (u16*)pA;
  u16* ffh = (u16*)pA;
  float* a1pre = (float*)pB;
  float* a2pre = (float*)pB;
  float* part0 = (float*)pB;
  float* part1 = (float*)pC;         // spans pC+pD (16.8MB)
  u16* ybf = (u16*)pC;
  u16* VT = (u16*)pC;
  u16* a1bf = (u16*)pC;
  u16* attn2bf = (u16*)pC;
  u16* cat = (u16*)pD;
  u16* a2bf = (u16*)pD;
  u16* xbf = (u16*)pE;
  u16* xT = (u16*)pF;
  u16* Bqkv = (u16*)pG;                       // 6,291,456 B
  u16* W1T = (u16*)(pG + 6291456);            // 2,097,152
  u16* W2sumT = (u16*)(pG + 8388608);         // 2,097,152
  u16* Wf1T = (u16*)(pG + 10485760);          // 8,388,608
  u16* Wf2T = (u16*)(pG + 18874368);          // 8,388,608
  float* bqkvf = (float*)(pG + 27262976);     // 12,288
  float* rowinv = (float*)(pG + 27275264);    // 16,384

  // ---- precompute / conversions ----
  cvt2_bf16_kernel<<<8192, 256, 0, stream>>>(y, x, ybf, xbf);
  tr_f32_bf16_kernel<<<dim3(SD / 32, SS / 32, SB), 256, 0, stream>>>(
      x, xT, SS, SD, (long)SS * SD, (long)SS * SD);
  tr_wqkv_kernel<<<dim3(2, 32, 48), 256, 0, stream>>>(Wq, Wk, Wv, Bqkv);
  tr_f32_bf16_kernel<<<dim3(32, 32, 1), 256, 0, stream>>>(W1, W1T, SD, SD, 0, 0);
  reduce_w2t_kernel<<<dim3(16, 16), 256, 0, stream>>>(W2, W2sumT);
  tr_f32_bf16_kernel<<<dim3(SDF / 32, SD / 32, 1), 256, 0, stream>>>(
      Wf1, Wf1T, SD, SDF, 0, 0);
  tr_f32_bf16_kernel<<<dim3(SD / 32, SDF / 32, 1), 256, 0, stream>>>(
      Wf2, Wf2T, SDF, SD, 0, 0);
  pack_bias_kernel<<<12, 256, 0, stream>>>(bq, bk, bv, bqkvf);

  // ---- fused QKV projection: [4096,1024] @ [3072,1024]^T -> C3 bf16 ----
  gemm_bt_kernel<1, false, true, false><<<dim3(24, 32, 1), 256, 0, stream>>>(
      ybf, Bqkv, bqkvf, C3, NBS, 3072, SD, SD, SD, 1.f, 0, 0, 0, 0, 0);
  vt_kernel<<<dim3(SS / 64, SB * SH), 256, 0, stream>>>(C3, VT);
  // ---- causal flash self-attention (1024 blocks, XCD-clustered) ----
  flash_kernel<<<1024, 256, 0, stream>>>(C3, VT, cat);
  // ---- a1 = LN(y + cat@W1 + b1) -> bf16  (m-clustered swizzle) ----
  gemm_bt64_kernel<0, false, true, false, true><<<512, 256, 0, stream>>>(
      cat, W1T, b1, a1pre, NBS, SD, SD, 1.f, 0, 0, 0, nullptr, 16, 32);
  ln_res_kernel<true><<<NBS, 256, 0, stream>>>(a1pre, y, ln1_g, ln1_b, a1bf);
  // ---- cross-attention: P_un = exp(a1@x^T/8) bf16; rowinv; attn2 w/ scale --
  gemm_bt_kernel<2, false, false, false><<<dim3(16, 16, SB), 256, 0, stream>>>(
      a1bf, xbf, nullptr, p2un, SS, SS, SD, SD, SD, 0.125f, (long)SS * SD,
      (long)SS * SD, (long)SS * SS, 0, 0);
  rowinv_kernel<<<NBS, 256, 0, stream>>>(p2un, rowinv);
  gemm_bt64_kernel<1, false, false, true, true><<<512, 256, 0, stream>>>(
      p2un, xT, nullptr, attn2bf, SS, SD, SS, 1.f, (long)SS * SS,
      (long)SS * SD, (long)SS * SD, rowinv, 16, 16);
  // ---- a2 = LN(y + attn2@W2sum + b2) ----
  gemm_bt64_kernel<0, false, true, false, true><<<512, 256, 0, stream>>>(
      attn2bf, W2sumT, b2, a2pre, NBS, SD, SD, 1.f, 0, 0, 0, nullptr, 16, 32);
  ln_res_kernel<true><<<NBS, 256, 0, stream>>>(a2pre, y, ln2_g, ln2_b, a2bf);
  // ---- FFN1: 128x128 (R7-proven config) ----
  gemm_bt_kernel<1, true, true, false><<<dim3(32, 32, 1), 256, 0, stream>>>(
      a2bf, Wf1T, bf1, ffh, NBS, SDF, SD, SD, SD, 1.f, 0, 0, 0, 0, 0);
  // ---- FFN2 split-K=2, m-clustered swizzle ----
  gemm_bt_kernel<0, false, false, true><<<512, 256, 0, stream>>>(
      ffh, Wf2T, nullptr, part0, NBS, SD, SDF / 2, SDF, SDF, 1.f, SDF / 2,
      SDF / 2, (long)NBS * SD, 8, 32);
  ln_res2_kernel<<<NBS, 256, 0, stream>>>(part0, part1, y, bf2, ln3_g, ln3_b,
                                          (float*)d_out);
}